// Round 3
// baseline (176.203 us; speedup 1.0000x reference)
//
#include <hip/hip_runtime.h>

#define N_NODES 100000
#define DEG 16
#define D_DIM 128
#define U_DIM 128
#define FSTRIDE 136   // bf16 LDS row stride: 272 B -> 68 dwords -> conflicts <= 2-way

typedef __bf16 bf16x8 __attribute__((ext_vector_type(8)));
typedef float f32x4 __attribute__((ext_vector_type(4)));
typedef unsigned int u32x4 __attribute__((ext_vector_type(4)));

__device__ __forceinline__ unsigned short f2bf(float x) {
    // round-to-nearest-even fp32 -> bf16 (inputs finite)
    unsigned int u = __float_as_uint(x);
    u += 0x7fffu + ((u >> 16) & 1u);
    return (unsigned short)(u >> 16);
}
__device__ __forceinline__ unsigned int pack2(float a, float b) {
    return (unsigned int)f2bf(a) | ((unsigned int)f2bf(b) << 16);
}

// W fp32 [K=128][U=128] row-major -> WT bf16 [U][K] (A-fragment friendly: k contiguous)
__global__ void cast_w_kernel(const float* __restrict__ W,
                              unsigned short* __restrict__ WT) {
    int t = blockIdx.x * 256 + threadIdx.x;   // t < 16384
    int k = t >> 7, n = t & 127;
    WT[n * 128 + k] = f2bf(W[t]);
}

// Y[n][u] = feat[n,:] @ W[:,u] + b[u], stored bf16 row-major [N][128].
// feat tile (128 nodes) staged ONCE per block into LDS as bf16. A = W^T
// loop-invariant fragments; B from LDS ds_read_b128. D[m=u][n=node] -> uint2 stores.
__global__ __launch_bounds__(256)
void ymat_kernel(const float* __restrict__ feat,
                 const unsigned short* __restrict__ WT,   // bf16 [U][K]
                 const float* __restrict__ bias,
                 unsigned short* __restrict__ Y) {
    __shared__ __align__(16) unsigned short ftile[128 * FSTRIDE];
    const int lane = threadIdx.x & 63;
    const int wv = threadIdx.x >> 6;
    const int quad = lane >> 4;
    const int l15 = lane & 15;
    const int n0 = blockIdx.x * 128;
    const int u_base = wv * 32;

    // ---- stage: 16384 floats, thread t handles float4 indices j*256+t (1 KB/instr/wave)
    {
        const int t = threadIdx.x;
        #pragma unroll
        for (int j = 0; j < 16; ++j) {
            const int i = j * 256 + t;          // float4 index in tile
            const int row = i >> 5;
            const int col = (i & 31) * 4;
            const int rowc = (n0 + row < N_NODES) ? (n0 + row) : (N_NODES - 1);
            const float4 v = *(const float4*)(feat + (size_t)rowc * D_DIM + col);
            ushort4 s;
            s.x = f2bf(v.x); s.y = f2bf(v.y); s.z = f2bf(v.z); s.w = f2bf(v.w);
            *(ushort4*)&ftile[row * FSTRIDE + col] = s;
        }
    }

    // A fragments: A[m=l15 -> u][k = kc*32+quad*8+j]
    bf16x8 afr[2][4];
    #pragma unroll
    for (int ni = 0; ni < 2; ++ni) {
        const int u = u_base + ni * 16 + l15;
        #pragma unroll
        for (int kc = 0; kc < 4; ++kc)
            afr[ni][kc] = *(const bf16x8*)(WT + u * 128 + kc * 32 + quad * 8);
    }
    // bias for D rows: u = u_base + ni*16 + quad*4 + r
    const float4 bv0 = *(const float4*)(bias + u_base + quad * 4);
    const float4 bv1 = *(const float4*)(bias + u_base + 16 + quad * 4);

    __syncthreads();

    #pragma unroll
    for (int mi = 0; mi < 8; ++mi) {
        const int node = n0 + mi * 16 + l15;
        bf16x8 bfr[4];
        #pragma unroll
        for (int kc = 0; kc < 4; ++kc)   // B[k][n]: n=l15 -> node row in LDS
            bfr[kc] = *(const bf16x8*)&ftile[(mi * 16 + l15) * FSTRIDE + kc * 32 + quad * 8];
        f32x4 acc0 = (f32x4){0.f, 0.f, 0.f, 0.f};
        f32x4 acc1 = (f32x4){0.f, 0.f, 0.f, 0.f};
        #pragma unroll
        for (int kc = 0; kc < 4; ++kc) {
            acc0 = __builtin_amdgcn_mfma_f32_16x16x32_bf16(afr[0][kc], bfr[kc], acc0, 0, 0, 0);
            acc1 = __builtin_amdgcn_mfma_f32_16x16x32_bf16(afr[1][kc], bfr[kc], acc1, 0, 0, 0);
        }
        if (node < N_NODES) {
            unsigned int* yp = (unsigned int*)(Y + (size_t)node * U_DIM + u_base + quad * 4);
            uint2 s0, s1;
            s0.x = pack2(acc0[0] + bv0.x, acc0[1] + bv0.y);
            s0.y = pack2(acc0[2] + bv0.z, acc0[3] + bv0.w);
            s1.x = pack2(acc1[0] + bv1.x, acc1[1] + bv1.y);
            s1.y = pack2(acc1[2] + bv1.z, acc1[3] + bv1.w);
            *(uint2*)yp = s0;
            *(uint2*)(yp + 8) = s1;   // +16 ushorts
        }
    }
}

// out[n, phase*64 : +64] = relu( (sum_e w_e * Y[col_e, half]) / (sum_e w_e) )
// Two u-phases via grid ordering (12.8 MB pool/phase). 8 lanes/node, uint4
// gathers: one instr = 8 nodes x full 128 B half-row (aligned, fully-used lines).
// Gathers issued as asm-volatile global_load_dwordx4: the compiler re-rolled
// every HLL formulation to ~4 outstanding lines (VGPR=36 twice); volatile asm
// pins all 16 in flight. One vmcnt(0) + sched_barrier(0) (rule #18) before use.
// Little's law: 58% occ x 16 lines/wave x 8 instr-depth >> 135 lines/CU needed
// to saturate ~6 TB/s; previous ~4-deep codegen predicts 3.4 TB/s (measured 3.7).
__global__ __launch_bounds__(256, 4)
void agg_kernel(const unsigned short* __restrict__ Y,
                const int* __restrict__ cols,
                const float* __restrict__ wts,
                float* __restrict__ out) {
    const int phase = (blockIdx.x >= 3125) ? 1 : 0;
    const int nb = blockIdx.x - phase * 3125;
    const int node = nb * 32 + (threadIdx.x >> 3);   // exact: 3125*32 = N_NODES
    const int ubase = phase * 64 + (threadIdx.x & 7) * 8;   // owns 8 dims
    const int e0 = node * DEG;

    int cc[DEG];
    float ww[DEG];
    #pragma unroll
    for (int q = 0; q < 4; ++q) {
        const int4 c4 = *(const int4*)(cols + e0 + 4 * q);
        const float4 w4 = *(const float4*)(wts + e0 + 4 * q);
        cc[4 * q + 0] = c4.x; cc[4 * q + 1] = c4.y;
        cc[4 * q + 2] = c4.z; cc[4 * q + 3] = c4.w;
        ww[4 * q + 0] = w4.x; ww[4 * q + 1] = w4.y;
        ww[4 * q + 2] = w4.z; ww[4 * q + 3] = w4.w;
    }
    float den = 0.f;
    #pragma unroll
    for (int e = 0; e < DEG; ++e) den += ww[e];

    // ---- 16 gathers pinned in flight via volatile asm (compiler cannot re-roll)
    const unsigned short* ybase = Y + ubase;
    u32x4 p[DEG];
    #pragma unroll
    for (int e = 0; e < DEG; ++e) {
        const unsigned long long a =
            (unsigned long long)(ybase + (size_t)cc[e] * U_DIM);
        asm volatile("global_load_dwordx4 %0, %1, off" : "=v"(p[e]) : "v"(a));
    }
    asm volatile("s_waitcnt vmcnt(0)" ::: "memory");
    __builtin_amdgcn_sched_barrier(0);   // rule #18: no consumer hoists above the wait

    float a0 = 0.f, a1 = 0.f, a2 = 0.f, a3 = 0.f;
    float a4 = 0.f, a5 = 0.f, a6 = 0.f, a7 = 0.f;
    #pragma unroll
    for (int e = 0; e < DEG; ++e) {
        const float w = ww[e];
        a0 = fmaf(w, __uint_as_float(p[e][0] << 16), a0);
        a1 = fmaf(w, __uint_as_float(p[e][0] & 0xffff0000u), a1);
        a2 = fmaf(w, __uint_as_float(p[e][1] << 16), a2);
        a3 = fmaf(w, __uint_as_float(p[e][1] & 0xffff0000u), a3);
        a4 = fmaf(w, __uint_as_float(p[e][2] << 16), a4);
        a5 = fmaf(w, __uint_as_float(p[e][2] & 0xffff0000u), a5);
        a6 = fmaf(w, __uint_as_float(p[e][3] << 16), a6);
        a7 = fmaf(w, __uint_as_float(p[e][3] & 0xffff0000u), a7);
    }
    const float inv = 1.0f / den;           // den >= 0.1*16
    f32x4 o0, o1;
    o0[0] = fmaxf(a0 * inv, 0.f); o0[1] = fmaxf(a1 * inv, 0.f);
    o0[2] = fmaxf(a2 * inv, 0.f); o0[3] = fmaxf(a3 * inv, 0.f);
    o1[0] = fmaxf(a4 * inv, 0.f); o1[1] = fmaxf(a5 * inv, 0.f);
    o1[2] = fmaxf(a6 * inv, 0.f); o1[3] = fmaxf(a7 * inv, 0.f);
    f32x4* op = (f32x4*)(out + (size_t)node * U_DIM + ubase);
    __builtin_nontemporal_store(o0, op);    // write-once stream: don't evict Y from L2
    __builtin_nontemporal_store(o1, op + 1);
}

extern "C" void kernel_launch(void* const* d_in, const int* in_sizes, int n_in,
                              void* d_out, int out_size, void* d_ws, size_t ws_size,
                              hipStream_t stream) {
    const float* feat = (const float*)d_in[0];
    // d_in[1] = edge_rows: unused — rows are arange(E)//DEG, node i owns edges [16i,16i+16)
    const int* cols  = (const int*)d_in[2];
    const float* wts = (const float*)d_in[3];
    const float* W   = (const float*)d_in[4];
    const float* b   = (const float*)d_in[5];
    float* out = (float*)d_out;

    unsigned short* wt_bf = (unsigned short*)d_ws;                    // 32 KB bf16 [U][K]
    unsigned short* Y     = (unsigned short*)((char*)d_ws + 32768);   // 25.6 MB bf16 [N][128]

    cast_w_kernel<<<16384 / 256, 256, 0, stream>>>(W, wt_bf);

    const int nblocks = (N_NODES + 127) / 128;   // 782
    ymat_kernel<<<nblocks, 256, 0, stream>>>(feat, wt_bf, b, Y);

    agg_kernel<<<6250, 256, 0, stream>>>(Y, cols, wts, out);
}